// Round 7
// baseline (26122.089 us; speedup 1.0000x reference)
//
#include <hip/hip_runtime.h>
#include <hip/hip_bf16.h>
#include <hip/hip_fp16.h>

#define S_LEN 8192
#define LC 16
#define CE 64
#define CH 64
#define WE 128
#define NTAGS 50

using bf16 = __hip_bfloat16;
typedef unsigned int u32;
typedef unsigned long long u64;

__device__ __forceinline__ float bfbits2f(unsigned short u) {
    union { unsigned int i; float f; } v; v.i = ((unsigned int)u) << 16; return v.f;
}
__device__ __forceinline__ float sigm(float x) {
    return __builtin_amdgcn_rcpf(1.0f + __expf(-x));
}
__device__ __forceinline__ float tanh_fast(float x) {
    return 1.0f - 2.0f * __builtin_amdgcn_rcpf(__expf(2.0f * x) + 1.0f);
}

// dtype-generic accessors ----------------------------------------------------
template <bool BF>
__device__ __forceinline__ float ld1(const void* p, size_t i) {
    if constexpr (BF) return bfbits2f(((const unsigned short*)p)[i]);
    else              return ((const float*)p)[i];
}
template <bool BF>
__device__ __forceinline__ float4 ld4(const void* p, size_t i) {  // elems i..i+3
    if constexpr (BF) {
        const ushort4 s = *reinterpret_cast<const ushort4*>((const unsigned short*)p + i);
        return make_float4(bfbits2f(s.x), bfbits2f(s.y), bfbits2f(s.z), bfbits2f(s.w));
    } else {
        return *reinterpret_cast<const float4*>((const float*)p + i);
    }
}
template <bool BF>
__device__ __forceinline__ void st1(void* p, size_t i, float v) {
    if constexpr (BF) ((bf16*)p)[i] = __float2bfloat16(v);
    else              ((float*)p)[i] = v;
}

// f16-pair helpers for the recurrent matvec (HW-validated R1/R2/R5/R6) ------
typedef _Float16 h2t __attribute__((ext_vector_type(2)));

__device__ __forceinline__ u32 pk2(float a, float b) {        // RTE pack
    __half2 h = __floats2half2_rn(a, b);
    u32 r; __builtin_memcpy(&r, &h, 4); return r;
}
__device__ __forceinline__ float fdot2u(u32 a, u32 b, float c) {
#if __has_builtin(__builtin_amdgcn_fdot2)
    h2t av, bv;
    __builtin_memcpy(&av, &a, 4);
    __builtin_memcpy(&bv, &b, 4);
    return __builtin_amdgcn_fdot2(av, bv, c, false);
#else
    __half2 ah, bh;
    __builtin_memcpy(&ah, &a, 4);
    __builtin_memcpy(&bh, &b, 4);
    c = fmaf(__half2float(ah.x), __half2float(bh.x), c);
    c = fmaf(__half2float(ah.y), __half2float(bh.y), c);
    return c;
#endif
}

// ---------------------------------------------------------------------------
// Detector: classify float-tensor dtype from char_emb's first 256 ushorts.
// ---------------------------------------------------------------------------
__global__ void kdetect(const void* emb, u32* flag) {
    const int j = threadIdx.x;           // 64 lanes
    int s = 0;
    #pragma unroll
    for (int k = 0; k < 4; ++k) {
        const unsigned short u = ((const unsigned short*)emb)[j * 4 + k];
        const int e = (u >> 7) & 0xFF;
        s += (e >= 100 && e <= 133) ? 1 : 0;
    }
    #pragma unroll
    for (int off = 32; off >= 1; off >>= 1) s += __shfl_xor(s, off, 64);
    if (j == 0) *flag = (s >= 200) ? 1u : 0u;
}

// ---------------------------------------------------------------------------
// Kernel A: char LSTM. 8 words/block, 256 threads (thread j = gate row j).
// ---------------------------------------------------------------------------
template <bool BF>
__global__ __launch_bounds__(256, 2) void kchar(
        const u32* __restrict__ dtf,
        const int* __restrict__ char_idxs, const int* __restrict__ char_lens,
        const void* __restrict__ char_emb,
        const void* __restrict__ Wih, const void* __restrict__ Whh,
        const void* __restrict__ bih, const void* __restrict__ bhh,
        float* __restrict__ cfeat) {
    if ((*dtf != 0u) != BF) return;
    const int j = threadIdx.x;
    const int w0 = blockIdx.x * 8;

    __shared__ __align__(16) float emb_lds[128 * CE];     // 32 KB
    __shared__ __align__(16) float gates_lds[8 * 256];    // 8 KB
    __shared__ __align__(16) float h_lds[8 * CH];
    __shared__ __align__(16) float c_lds[8 * CH];
    __shared__ int cidx_lds[8 * LC];
    __shared__ int len_lds[8];

    {
        float4* emb4 = reinterpret_cast<float4*>(emb_lds);
        #pragma unroll
        for (int i = 0; i < 8; ++i) {
            const int c = i * 256 + j;
            emb4[c] = ld4<BF>(char_emb, (size_t)c * 4);
        }
    }
    if (j < 128) cidx_lds[j] = char_idxs[w0 * LC + j];
    if (j < 8)   len_lds[j]  = char_lens[w0 + j];
    h_lds[j] = 0.f; h_lds[j + 256] = 0.f;
    c_lds[j] = 0.f; c_lds[j + 256] = 0.f;

    float4 wih4[16], whh4[16];
    #pragma unroll
    for (int kc = 0; kc < 16; ++kc) {
        wih4[kc] = ld4<BF>(Wih, (size_t)j * CE + kc * 4);
        whh4[kc] = ld4<BF>(Whh, (size_t)j * CH + kc * 4);
    }
    const float bias = ld1<BF>(bih, j) + ld1<BF>(bhh, j);
    __syncthreads();

    for (int t = 0; t < LC; ++t) {
        for (int w = 0; w < 8; ++w) {
            const int ci = cidx_lds[w * LC + t];
            const float4* x4  = reinterpret_cast<const float4*>(emb_lds + ci * CE);
            const float4* hh4 = reinterpret_cast<const float4*>(h_lds + w * CH);
            float a0 = 0.f, a1 = 0.f, a2 = 0.f, a3 = 0.f;
            #pragma unroll
            for (int kc = 0; kc < 16; ++kc) {
                const float4 xv = x4[kc]; const float4 hv = hh4[kc];
                const float4 wi = wih4[kc]; const float4 wh = whh4[kc];
                a0 = fmaf(wi.x, xv.x, a0); a1 = fmaf(wi.y, xv.y, a1);
                a2 = fmaf(wi.z, xv.z, a2); a3 = fmaf(wi.w, xv.w, a3);
                a0 = fmaf(wh.x, hv.x, a0); a1 = fmaf(wh.y, hv.y, a1);
                a2 = fmaf(wh.z, hv.z, a2); a3 = fmaf(wh.w, hv.w, a3);
            }
            gates_lds[w * 256 + j] = bias + ((a0 + a1) + (a2 + a3));
        }
        __syncthreads();
        #pragma unroll
        for (int rep = 0; rep < 2; ++rep) {
            const int p = j + rep * 256;       // p = w*64 + u
            const int w = p >> 6, u = p & 63;
            const float ig = gates_lds[w * 256 + u];
            const float fg = gates_lds[w * 256 + 64 + u];
            const float gg = gates_lds[w * 256 + 128 + u];
            const float og = gates_lds[w * 256 + 192 + u];
            const float cn = sigm(fg) * c_lds[p] + sigm(ig) * tanh_fast(gg);
            const float hn = sigm(og) * tanh_fast(cn);
            c_lds[p] = cn; h_lds[p] = hn;
            if (t == len_lds[w] - 1)
                cfeat[(size_t)(w0 + w) * CH + u] = hn;
        }
        __syncthreads();
    }
}

// ---------------------------------------------------------------------------
// Kernel B: Gx ring chunk. 16 words/block.
// ---------------------------------------------------------------------------
template <bool BF>
__global__ __launch_bounds__(256) void kgx(
        const u32* __restrict__ dtf,
        int t0, const int* __restrict__ word_idxs, const float* __restrict__ cfeat,
        const void* __restrict__ wemb, const void* __restrict__ Wih,
        const void* __restrict__ bih, const void* __restrict__ bhh,
        float* __restrict__ Gxr) {
    if ((*dtf != 0u) != BF) return;
    const int j = threadIdx.x;
    const int wr0 = blockIdx.x * 16;       // ring row base
    const int w0g = t0 + wr0;              // global word base
    __shared__ __align__(16) float wx[16 * 192];
    __shared__ int widx[16];
    if (j < 16) widx[j] = word_idxs[w0g + j];
    __syncthreads();
    {
        const int w = j >> 4, ch = j & 15;
        const size_t eb = (size_t)widx[w] * WE + ch * 8;
        const float4 f0 = ld4<BF>(wemb, eb), f1 = ld4<BF>(wemb, eb + 4);
        float4* dst = reinterpret_cast<float4*>(wx + w * 192 + ch * 8);
        dst[0] = f0; dst[1] = f1;
        const float4 cf = *reinterpret_cast<const float4*>(
            cfeat + (size_t)(w0g + w) * CH + ch * 4);
        *reinterpret_cast<float4*>(wx + w * 192 + WE + ch * 4) = cf;
    }
    __syncthreads();

    for (int g = 0; g < 4; ++g) {
        const int r = g * 256 + j;
        float acc[16];
        #pragma unroll
        for (int w = 0; w < 16; ++w) acc[w] = 0.f;
        #pragma unroll 8
        for (int kc = 0; kc < 48; ++kc) {
            const float4 wv = ld4<BF>(Wih, (size_t)r * 192 + kc * 4);
            #pragma unroll
            for (int w = 0; w < 16; ++w) {
                const float4 xv = *reinterpret_cast<const float4*>(wx + w * 192 + kc * 4);
                acc[w] = fmaf(wv.x, xv.x, acc[w]);
                acc[w] = fmaf(wv.y, xv.y, acc[w]);
                acc[w] = fmaf(wv.z, xv.z, acc[w]);
                acc[w] = fmaf(wv.w, xv.w, acc[w]);
            }
        }
        const float bias = ld1<BF>(bih, r) + ld1<BF>(bhh, r);
        #pragma unroll
        for (int w = 0; w < 16; ++w)
            Gxr[(size_t)(wr0 + w) * 1024 + r] = acc[w] + bias;
    }
}

// ---------------------------------------------------------------------------
// Kernel C (R7): word LSTM on ONE CU, 256 threads (4 waves, 1 wave/SIMD).
// R6 post-mortem: the single-CU design was right but hipcc's allocator gave
// 128 VGPRs vs the ~240 needed -> ~229KB/step scratch reload ≈ the whole
// 3800cy step time. The allocator ignores __launch_bounds__'s budget and
// targets its own occupancy heuristic (R2: 108, R5: 136, R6: 128 — same
// pattern). Fix: __attribute__((amdgpu_waves_per_eu(1,1))) pins the target
// at 1 wave/EU -> full 512-reg file usable (m08: no spill through ~450).
//
//  * Thread j owns UNIT j — all 4 gate rows {j, 256+j, 512+j, 768+j}:
//    gate math fully thread-local (no shuffles, c in register).
//  * Weights/row: 96 f16-pair dwords VGPR (4x96=384 regs) + 32 dwords LDS
//    wt[4][8][256] (128KB, lane-contiguous ds_read_b128, conflict-free).
//  * h: 128 f16-pair dwords, double-buffered LDS h2[2][128]; uniform
//    (broadcast) uint4 reads; __syncthreads between write & read is the
//    memory clobber that makes the u32-write/uint4-read pun safe (R4).
//  * One __syncthreads per step. Budget: VALU 512 dot2 x 2cy = 1024cy/SIMD;
//    DS ~1550cy weight + ~250cy h (overlapped w/ VALU) -> ~2000cy/step.
//  * h/c carried across chunk launches via hsave/csave (stream-ordered).
// ---------------------------------------------------------------------------
template <bool BF>
__global__ __launch_bounds__(256)
__attribute__((amdgpu_waves_per_eu(1, 1)))
void kwlstm(
        const u32* __restrict__ dtf,
        int t0, int t1, const void* __restrict__ whh,
        const float* __restrict__ Gxr,
        float* __restrict__ hallr, u32* __restrict__ hsave,
        float* __restrict__ csave) {
    if ((*dtf != 0u) != BF) return;
    const int j = threadIdx.x;             // unit 0..255
    const int ri = j, rf = 256 + j, rg = 512 + j, ro = 768 + j;

    __shared__ __align__(16) uint4 wt[4][8][256];   // 128 KB weight tail
    __shared__ __align__(16) u32 h2[2][128];        // h as f16 pairs, dbuf

    // ---- init: VGPR weight blocks (cols 0..191 of each row; 96 dwords) ----
    u32 wgi[96], wgf[96], wgg[96], wgo[96];
    #pragma unroll
    for (int kc = 0; kc < 48; ++kc) {
        const float4 v = ld4<BF>(whh, (size_t)ri * 256 + kc * 4);
        wgi[2 * kc] = pk2(v.x, v.y); wgi[2 * kc + 1] = pk2(v.z, v.w);
    }
    #pragma unroll
    for (int kc = 0; kc < 48; ++kc) {
        const float4 v = ld4<BF>(whh, (size_t)rf * 256 + kc * 4);
        wgf[2 * kc] = pk2(v.x, v.y); wgf[2 * kc + 1] = pk2(v.z, v.w);
    }
    #pragma unroll
    for (int kc = 0; kc < 48; ++kc) {
        const float4 v = ld4<BF>(whh, (size_t)rg * 256 + kc * 4);
        wgg[2 * kc] = pk2(v.x, v.y); wgg[2 * kc + 1] = pk2(v.z, v.w);
    }
    #pragma unroll
    for (int kc = 0; kc < 48; ++kc) {
        const float4 v = ld4<BF>(whh, (size_t)ro * 256 + kc * 4);
        wgo[2 * kc] = pk2(v.x, v.y); wgo[2 * kc + 1] = pk2(v.z, v.w);
    }
    // ---- init: LDS weight tails (cols 192..255; 32 dwords = 8 uint4/row) --
    #pragma unroll
    for (int qi = 0; qi < 8; ++qi) {
        const float4 a = ld4<BF>(whh, (size_t)ri * 256 + 192 + qi * 8);
        const float4 b = ld4<BF>(whh, (size_t)ri * 256 + 192 + qi * 8 + 4);
        wt[0][qi][j] = make_uint4(pk2(a.x, a.y), pk2(a.z, a.w),
                                  pk2(b.x, b.y), pk2(b.z, b.w));
    }
    #pragma unroll
    for (int qi = 0; qi < 8; ++qi) {
        const float4 a = ld4<BF>(whh, (size_t)rf * 256 + 192 + qi * 8);
        const float4 b = ld4<BF>(whh, (size_t)rf * 256 + 192 + qi * 8 + 4);
        wt[1][qi][j] = make_uint4(pk2(a.x, a.y), pk2(a.z, a.w),
                                  pk2(b.x, b.y), pk2(b.z, b.w));
    }
    #pragma unroll
    for (int qi = 0; qi < 8; ++qi) {
        const float4 a = ld4<BF>(whh, (size_t)rg * 256 + 192 + qi * 8);
        const float4 b = ld4<BF>(whh, (size_t)rg * 256 + 192 + qi * 8 + 4);
        wt[2][qi][j] = make_uint4(pk2(a.x, a.y), pk2(a.z, a.w),
                                  pk2(b.x, b.y), pk2(b.z, b.w));
    }
    #pragma unroll
    for (int qi = 0; qi < 8; ++qi) {
        const float4 a = ld4<BF>(whh, (size_t)ro * 256 + 192 + qi * 8);
        const float4 b = ld4<BF>(whh, (size_t)ro * 256 + 192 + qi * 8 + 4);
        wt[3][qi][j] = make_uint4(pk2(a.x, a.y), pk2(a.z, a.w),
                                  pk2(b.x, b.y), pk2(b.z, b.w));
    }
    // ---- init: state ----
    if (j < 128) {
        h2[0][j] = 0u; h2[1][j] = 0u;
        if (t0 > 0) h2[t0 & 1][j] = hsave[j];
    }
    float c_reg = 0.f;
    if (t0 > 0) c_reg = csave[j];

    // gx for step t0 (one value per gate row)
    float gxi = Gxr[(size_t)0 * 1024 + ri];
    float gxf = Gxr[(size_t)0 * 1024 + rf];
    float gxg = Gxr[(size_t)0 * 1024 + rg];
    float gxo = Gxr[(size_t)0 * 1024 + ro];
    __syncthreads();

    for (int t = t0; t < t1; ++t) {
        const int p = t & 1;
        // prefetch gx for t+1 (L2-resident ring; in flight during the dot)
        float gni = 0.f, gnf = 0.f, gng = 0.f, gno = 0.f;
        if (t + 1 < t1) {
            const size_t base = (size_t)(t + 1 - t0) * 1024;
            gni = Gxr[base + ri]; gnf = Gxr[base + rf];
            gng = Gxr[base + rg]; gno = Gxr[base + ro];
        }

        float ai0 = 0.f, ai1 = 0.f, af0 = 0.f, af1 = 0.f;
        float ag0 = 0.f, ag1 = 0.f, ao0 = 0.f, ao1 = 0.f;
        if (t > 0) {
            const uint4* h4 = reinterpret_cast<const uint4*>(&h2[p][0]);
            #pragma unroll
            for (int q = 0; q < 24; ++q) {         // h dwords 0..95 (VGPR w)
                const uint4 hv = h4[q];            // uniform broadcast read
                ai0 = fdot2u(wgi[4 * q + 0], hv.x, ai0);
                ai1 = fdot2u(wgi[4 * q + 1], hv.y, ai1);
                ai0 = fdot2u(wgi[4 * q + 2], hv.z, ai0);
                ai1 = fdot2u(wgi[4 * q + 3], hv.w, ai1);
                af0 = fdot2u(wgf[4 * q + 0], hv.x, af0);
                af1 = fdot2u(wgf[4 * q + 1], hv.y, af1);
                af0 = fdot2u(wgf[4 * q + 2], hv.z, af0);
                af1 = fdot2u(wgf[4 * q + 3], hv.w, af1);
                ag0 = fdot2u(wgg[4 * q + 0], hv.x, ag0);
                ag1 = fdot2u(wgg[4 * q + 1], hv.y, ag1);
                ag0 = fdot2u(wgg[4 * q + 2], hv.z, ag0);
                ag1 = fdot2u(wgg[4 * q + 3], hv.w, ag1);
                ao0 = fdot2u(wgo[4 * q + 0], hv.x, ao0);
                ao1 = fdot2u(wgo[4 * q + 1], hv.y, ao1);
                ao0 = fdot2u(wgo[4 * q + 2], hv.z, ao0);
                ao1 = fdot2u(wgo[4 * q + 3], hv.w, ao1);
            }
            #pragma unroll
            for (int qi = 0; qi < 8; ++qi) {       // h dwords 96..127 (LDS w)
                const uint4 hv = h4[24 + qi];
                const uint4 wi4 = wt[0][qi][j];
                const uint4 wf4 = wt[1][qi][j];
                const uint4 wg4 = wt[2][qi][j];
                const uint4 wo4 = wt[3][qi][j];
                ai0 = fdot2u(wi4.x, hv.x, ai0);
                ai1 = fdot2u(wi4.y, hv.y, ai1);
                ai0 = fdot2u(wi4.z, hv.z, ai0);
                ai1 = fdot2u(wi4.w, hv.w, ai1);
                af0 = fdot2u(wf4.x, hv.x, af0);
                af1 = fdot2u(wf4.y, hv.y, af1);
                af0 = fdot2u(wf4.z, hv.z, af0);
                af1 = fdot2u(wf4.w, hv.w, af1);
                ag0 = fdot2u(wg4.x, hv.x, ag0);
                ag1 = fdot2u(wg4.y, hv.y, ag1);
                ag0 = fdot2u(wg4.z, hv.z, ag0);
                ag1 = fdot2u(wg4.w, hv.w, ag1);
                ao0 = fdot2u(wo4.x, hv.x, ao0);
                ao1 = fdot2u(wo4.y, hv.y, ao1);
                ao0 = fdot2u(wo4.z, hv.z, ao0);
                ao1 = fdot2u(wo4.w, hv.w, ao1);
            }
        }
        const float gi_ = (ai0 + ai1) + gxi;
        const float gf_ = (af0 + af1) + gxf;
        const float gg_ = (ag0 + ag1) + gxg;
        const float go_ = (ao0 + ao1) + gxo;
        const float cn = sigm(gf_) * c_reg + sigm(gi_) * tanh_fast(gg_);
        c_reg = cn;
        const float hn = sigm(go_) * tanh_fast(cn);
        hallr[(size_t)(t - t0) * 256 + j] = hn;
        const float ho = __shfl_xor(hn, 1, 64);
        if (!(j & 1)) h2[p ^ 1][j >> 1] = pk2(hn, ho);
        __syncthreads();                           // h2[p^1] ready for t+1
        gxi = gni; gxf = gnf; gxg = gng; gxo = gno;
    }
    // ---- save state for next chunk ----
    if (j < 128) hsave[j] = h2[t1 & 1][j];
    csave[j] = c_reg;
}

// ---------------------------------------------------------------------------
// Kernel D: logits + log_softmax. One wave per word.
// ---------------------------------------------------------------------------
template <bool BF>
__global__ __launch_bounds__(64) void ktag(
        const u32* __restrict__ dtf,
        int t0, const float* __restrict__ hallr, const void* __restrict__ tagW,
        const void* __restrict__ tagb, void* __restrict__ out) {
    if ((*dtf != 0u) != BF) return;
    const int tr = blockIdx.x, j = threadIdx.x;
    const int t = t0 + tr;
    __shared__ __align__(16) float4 h4[64];
    h4[j] = reinterpret_cast<const float4*>(hallr + (size_t)tr * 256)[j];
    __syncthreads();
    float logit = -1e30f;
    if (j < NTAGS) {
        float a0 = 0.f, a1 = 0.f, a2 = 0.f, a3 = 0.f;
        #pragma unroll
        for (int kc = 0; kc < 64; ++kc) {
            const float4 wvv = ld4<BF>(tagW, (size_t)j * 256 + kc * 4);
            const float4 hv = h4[kc];
            a0 = fmaf(wvv.x, hv.x, a0); a1 = fmaf(wvv.y, hv.y, a1);
            a2 = fmaf(wvv.z, hv.z, a2); a3 = fmaf(wvv.w, hv.w, a3);
        }
        logit = ld1<BF>(tagb, j) + ((a0 + a1) + (a2 + a3));
    }
    float m = logit;
    #pragma unroll
    for (int off = 32; off >= 1; off >>= 1) m = fmaxf(m, __shfl_xor(m, off, 64));
    const float e = (j < NTAGS) ? __expf(logit - m) : 0.f;
    float ssum = e;
    #pragma unroll
    for (int off = 32; off >= 1; off >>= 1) ssum += __shfl_xor(ssum, off, 64);
    if (j < NTAGS)
        st1<BF>(out, (size_t)t * NTAGS + j, logit - m - __logf(ssum));
}

// ---------------------------------------------------------------------------
extern "C" void kernel_launch(void* const* d_in, const int* in_sizes, int n_in,
                              void* d_out, int out_size, void* d_ws, size_t ws_size,
                              hipStream_t stream) {
    const int*  word_idxs = (const int*)d_in[0];
    const int*  char_idxs = (const int*)d_in[1];
    const int*  char_lens = (const int*)d_in[2];
    const void* char_emb  = d_in[3];
    const void* char_Wih  = d_in[4];
    const void* char_Whh  = d_in[5];
    const void* char_bih  = d_in[6];
    const void* char_bhh  = d_in[7];
    const void* word_emb  = d_in[8];
    const void* word_Wih  = d_in[9];
    const void* word_Whh  = d_in[10];
    const void* word_bih  = d_in[11];
    const void* word_bhh  = d_in[12];
    const void* tag_W     = d_in[13];
    const void* tag_b     = d_in[14];

    // ws layout:
    //   [0,64)        dtflag u32
    //   [64,576)      hsave u32[128] (f16-pair h carry across chunks)
    //   [4224,5248)   csave f32[256]
    //   [8192,+2MB)   cfeat f32[8192*64]
    //   [ring0,...)   Gx ring f32[CT*1024] + hall ring f32[CT*256]
    char* ws = (char*)d_ws;
    u32*   dtf    = (u32*)(ws);
    u32*   hsave  = (u32*)(ws + 64);
    float* csave  = (float*)(ws + 4224);
    float* cfeat  = (float*)(ws + 8192);
    const size_t ring0 = 8192 + (size_t)S_LEN * CH * 4;

    int NC = 256;
    const int ncs[9] = {1, 2, 4, 8, 16, 32, 64, 128, 256};
    for (int i = 0; i < 9; ++i) {
        const int ct = S_LEN / ncs[i];
        if (ring0 + (size_t)ct * 5120 <= ws_size) { NC = ncs[i]; break; }
    }
    const int CT = S_LEN / NC;
    float* Gxr   = (float*)(ws + ring0);
    float* hallr = (float*)(ws + ring0 + (size_t)CT * 4096);

    hipLaunchKernelGGL(kdetect, dim3(1), dim3(64), 0, stream, char_emb, dtf);
    hipLaunchKernelGGL(kchar<true>,  dim3(S_LEN / 8), dim3(256), 0, stream,
                       dtf, char_idxs, char_lens, char_emb, char_Wih, char_Whh,
                       char_bih, char_bhh, cfeat);
    hipLaunchKernelGGL(kchar<false>, dim3(S_LEN / 8), dim3(256), 0, stream,
                       dtf, char_idxs, char_lens, char_emb, char_Wih, char_Whh,
                       char_bih, char_bhh, cfeat);
    for (int c = 0; c < NC; ++c) {
        const int t0 = c * CT;
        hipLaunchKernelGGL(kgx<true>,  dim3(CT / 16), dim3(256), 0, stream,
                           dtf, t0, word_idxs, cfeat, word_emb, word_Wih,
                           word_bih, word_bhh, Gxr);
        hipLaunchKernelGGL(kgx<false>, dim3(CT / 16), dim3(256), 0, stream,
                           dtf, t0, word_idxs, cfeat, word_emb, word_Wih,
                           word_bih, word_bhh, Gxr);
        hipLaunchKernelGGL(kwlstm<true>,  dim3(1), dim3(256), 0, stream,
                           dtf, t0, t0 + CT, word_Whh, Gxr, hallr, hsave, csave);
        hipLaunchKernelGGL(kwlstm<false>, dim3(1), dim3(256), 0, stream,
                           dtf, t0, t0 + CT, word_Whh, Gxr, hallr, hsave, csave);
        hipLaunchKernelGGL(ktag<true>,  dim3(CT), dim3(64), 0, stream,
                           dtf, t0, hallr, tag_W, tag_b, d_out);
        hipLaunchKernelGGL(ktag<false>, dim3(CT), dim3(64), 0, stream,
                           dtf, t0, hallr, tag_W, tag_b, d_out);
    }
}

// Round 8
// 14276.385 us; speedup vs baseline: 1.8297x; 1.8297x over previous
//
#include <hip/hip_runtime.h>
#include <hip/hip_bf16.h>
#include <hip/hip_fp16.h>

#define S_LEN 8192
#define LC 16
#define CE 64
#define CH 64
#define WE 128
#define NTAGS 50

using bf16 = __hip_bfloat16;
typedef unsigned int u32;
typedef unsigned long long u64;

__device__ __forceinline__ float bfbits2f(unsigned short u) {
    union { unsigned int i; float f; } v; v.i = ((unsigned int)u) << 16; return v.f;
}
__device__ __forceinline__ float sigm(float x) {
    return __builtin_amdgcn_rcpf(1.0f + __expf(-x));
}
__device__ __forceinline__ float tanh_fast(float x) {
    return 1.0f - 2.0f * __builtin_amdgcn_rcpf(__expf(2.0f * x) + 1.0f);
}

// dtype-generic accessors ----------------------------------------------------
template <bool BF>
__device__ __forceinline__ float ld1(const void* p, size_t i) {
    if constexpr (BF) return bfbits2f(((const unsigned short*)p)[i]);
    else              return ((const float*)p)[i];
}
template <bool BF>
__device__ __forceinline__ float4 ld4(const void* p, size_t i) {  // elems i..i+3
    if constexpr (BF) {
        const ushort4 s = *reinterpret_cast<const ushort4*>((const unsigned short*)p + i);
        return make_float4(bfbits2f(s.x), bfbits2f(s.y), bfbits2f(s.z), bfbits2f(s.w));
    } else {
        return *reinterpret_cast<const float4*>((const float*)p + i);
    }
}
template <bool BF>
__device__ __forceinline__ void st1(void* p, size_t i, float v) {
    if constexpr (BF) ((bf16*)p)[i] = __float2bfloat16(v);
    else              ((float*)p)[i] = v;
}

// f16-pair helpers for the recurrent matvec (HW-validated R1/R2/R5/R6) ------
typedef _Float16 h2t __attribute__((ext_vector_type(2)));

__device__ __forceinline__ u32 pk2(float a, float b) {        // RTE pack
    __half2 h = __floats2half2_rn(a, b);
    u32 r; __builtin_memcpy(&r, &h, 4); return r;
}
__device__ __forceinline__ float fdot2u(u32 a, u32 b, float c) {
#if __has_builtin(__builtin_amdgcn_fdot2)
    h2t av, bv;
    __builtin_memcpy(&av, &a, 4);
    __builtin_memcpy(&bv, &b, 4);
    return __builtin_amdgcn_fdot2(av, bv, c, false);
#else
    __half2 ah, bh;
    __builtin_memcpy(&ah, &a, 4);
    __builtin_memcpy(&bh, &b, 4);
    c = fmaf(__half2float(ah.x), __half2float(bh.x), c);
    c = fmaf(__half2float(ah.y), __half2float(bh.y), c);
    return c;
#endif
}

// ---------------------------------------------------------------------------
// Detector: classify float-tensor dtype from char_emb's first 256 ushorts.
// ---------------------------------------------------------------------------
__global__ void kdetect(const void* emb, u32* flag) {
    const int j = threadIdx.x;           // 64 lanes
    int s = 0;
    #pragma unroll
    for (int k = 0; k < 4; ++k) {
        const unsigned short u = ((const unsigned short*)emb)[j * 4 + k];
        const int e = (u >> 7) & 0xFF;
        s += (e >= 100 && e <= 133) ? 1 : 0;
    }
    #pragma unroll
    for (int off = 32; off >= 1; off >>= 1) s += __shfl_xor(s, off, 64);
    if (j == 0) *flag = (s >= 200) ? 1u : 0u;
}

// ---------------------------------------------------------------------------
// Kernel A: char LSTM. 8 words/block, 256 threads (thread j = gate row j).
// ---------------------------------------------------------------------------
template <bool BF>
__global__ __launch_bounds__(256, 2) void kchar(
        const u32* __restrict__ dtf,
        const int* __restrict__ char_idxs, const int* __restrict__ char_lens,
        const void* __restrict__ char_emb,
        const void* __restrict__ Wih, const void* __restrict__ Whh,
        const void* __restrict__ bih, const void* __restrict__ bhh,
        float* __restrict__ cfeat) {
    if ((*dtf != 0u) != BF) return;
    const int j = threadIdx.x;
    const int w0 = blockIdx.x * 8;

    __shared__ __align__(16) float emb_lds[128 * CE];     // 32 KB
    __shared__ __align__(16) float gates_lds[8 * 256];    // 8 KB
    __shared__ __align__(16) float h_lds[8 * CH];
    __shared__ __align__(16) float c_lds[8 * CH];
    __shared__ int cidx_lds[8 * LC];
    __shared__ int len_lds[8];

    {
        float4* emb4 = reinterpret_cast<float4*>(emb_lds);
        #pragma unroll
        for (int i = 0; i < 8; ++i) {
            const int c = i * 256 + j;
            emb4[c] = ld4<BF>(char_emb, (size_t)c * 4);
        }
    }
    if (j < 128) cidx_lds[j] = char_idxs[w0 * LC + j];
    if (j < 8)   len_lds[j]  = char_lens[w0 + j];
    h_lds[j] = 0.f; h_lds[j + 256] = 0.f;
    c_lds[j] = 0.f; c_lds[j + 256] = 0.f;

    float4 wih4[16], whh4[16];
    #pragma unroll
    for (int kc = 0; kc < 16; ++kc) {
        wih4[kc] = ld4<BF>(Wih, (size_t)j * CE + kc * 4);
        whh4[kc] = ld4<BF>(Whh, (size_t)j * CH + kc * 4);
    }
    const float bias = ld1<BF>(bih, j) + ld1<BF>(bhh, j);
    __syncthreads();

    for (int t = 0; t < LC; ++t) {
        for (int w = 0; w < 8; ++w) {
            const int ci = cidx_lds[w * LC + t];
            const float4* x4  = reinterpret_cast<const float4*>(emb_lds + ci * CE);
            const float4* hh4 = reinterpret_cast<const float4*>(h_lds + w * CH);
            float a0 = 0.f, a1 = 0.f, a2 = 0.f, a3 = 0.f;
            #pragma unroll
            for (int kc = 0; kc < 16; ++kc) {
                const float4 xv = x4[kc]; const float4 hv = hh4[kc];
                const float4 wi = wih4[kc]; const float4 wh = whh4[kc];
                a0 = fmaf(wi.x, xv.x, a0); a1 = fmaf(wi.y, xv.y, a1);
                a2 = fmaf(wi.z, xv.z, a2); a3 = fmaf(wi.w, xv.w, a3);
                a0 = fmaf(wh.x, hv.x, a0); a1 = fmaf(wh.y, hv.y, a1);
                a2 = fmaf(wh.z, hv.z, a2); a3 = fmaf(wh.w, hv.w, a3);
            }
            gates_lds[w * 256 + j] = bias + ((a0 + a1) + (a2 + a3));
        }
        __syncthreads();
        #pragma unroll
        for (int rep = 0; rep < 2; ++rep) {
            const int p = j + rep * 256;       // p = w*64 + u
            const int w = p >> 6, u = p & 63;
            const float ig = gates_lds[w * 256 + u];
            const float fg = gates_lds[w * 256 + 64 + u];
            const float gg = gates_lds[w * 256 + 128 + u];
            const float og = gates_lds[w * 256 + 192 + u];
            const float cn = sigm(fg) * c_lds[p] + sigm(ig) * tanh_fast(gg);
            const float hn = sigm(og) * tanh_fast(cn);
            c_lds[p] = cn; h_lds[p] = hn;
            if (t == len_lds[w] - 1)
                cfeat[(size_t)(w0 + w) * CH + u] = hn;
        }
        __syncthreads();
    }
}

// ---------------------------------------------------------------------------
// Kernel B: Gx ring chunk. 16 words/block.
// ---------------------------------------------------------------------------
template <bool BF>
__global__ __launch_bounds__(256) void kgx(
        const u32* __restrict__ dtf,
        int t0, const int* __restrict__ word_idxs, const float* __restrict__ cfeat,
        const void* __restrict__ wemb, const void* __restrict__ Wih,
        const void* __restrict__ bih, const void* __restrict__ bhh,
        float* __restrict__ Gxr) {
    if ((*dtf != 0u) != BF) return;
    const int j = threadIdx.x;
    const int wr0 = blockIdx.x * 16;       // ring row base
    const int w0g = t0 + wr0;              // global word base
    __shared__ __align__(16) float wx[16 * 192];
    __shared__ int widx[16];
    if (j < 16) widx[j] = word_idxs[w0g + j];
    __syncthreads();
    {
        const int w = j >> 4, ch = j & 15;
        const size_t eb = (size_t)widx[w] * WE + ch * 8;
        const float4 f0 = ld4<BF>(wemb, eb), f1 = ld4<BF>(wemb, eb + 4);
        float4* dst = reinterpret_cast<float4*>(wx + w * 192 + ch * 8);
        dst[0] = f0; dst[1] = f1;
        const float4 cf = *reinterpret_cast<const float4*>(
            cfeat + (size_t)(w0g + w) * CH + ch * 4);
        *reinterpret_cast<float4*>(wx + w * 192 + WE + ch * 4) = cf;
    }
    __syncthreads();

    for (int g = 0; g < 4; ++g) {
        const int r = g * 256 + j;
        float acc[16];
        #pragma unroll
        for (int w = 0; w < 16; ++w) acc[w] = 0.f;
        #pragma unroll 8
        for (int kc = 0; kc < 48; ++kc) {
            const float4 wv = ld4<BF>(Wih, (size_t)r * 192 + kc * 4);
            #pragma unroll
            for (int w = 0; w < 16; ++w) {
                const float4 xv = *reinterpret_cast<const float4*>(wx + w * 192 + kc * 4);
                acc[w] = fmaf(wv.x, xv.x, acc[w]);
                acc[w] = fmaf(wv.y, xv.y, acc[w]);
                acc[w] = fmaf(wv.z, xv.z, acc[w]);
                acc[w] = fmaf(wv.w, xv.w, acc[w]);
            }
        }
        const float bias = ld1<BF>(bih, r) + ld1<BF>(bhh, r);
        #pragma unroll
        for (int w = 0; w < 16; ++w)
            Gxr[(size_t)(wr0 + w) * 1024 + r] = acc[w] + bias;
    }
}

// ---------------------------------------------------------------------------
// Kernel C (R8): word LSTM on ONE CU = R6's exact structure (512 threads,
// 8 waves, thread owns 2 gate rows, 200 weight dwords VGPR + 114KB LDS tail,
// one barrier/step) with ONE change: amdgpu_waves_per_eu(2,2).
//
// Evidence chain: R6 requested ~240 VGPRs, allocator gave 128 (launch_bounds
// min-waves arg does NOT set the register budget) -> ~72 dwords/thread
// scratch-spilled -> 13.0ms. R7 proved amdgpu_waves_per_eu DOES control the
// allocator (VGPR_Count hit the 256 architected cap) but over-asked (430
// needed) -> scratch + 1 wave/SIMD -> 24.9ms. R8: R6's demand (~240) fits
// under 256; (2,2) matches the physical 8-waves-on-4-SIMDs residency and
// budgets 512-file/2 = 256 regs. Zero spill expected.
//
//  * thread j: unit u=j>>1, k=j&1. Rows: k=0 -> {u (gate i), 512+u (g)};
//    k=1 -> {256+u (f), 768+u (o)}. Cols 0..199 in VGPR (100 dwords/row),
//    cols 200..255 in LDS wl[14][512] (lane-contiguous, conflict-free).
//  * h: f16-pair dwords in double-buffered LDS h2[2][128]; uniform uint4
//    reads; the per-step __syncthreads is the write->read memory clobber
//    (R4 TBAA lesson).
//  * gates via 2x shfl_xor(1) + shfl_xor(2); k=0 lanes hold c, write hallr.
//  * h/c carried across chunk launches via hsave/csave (stream-ordered).
// ---------------------------------------------------------------------------
template <bool BF>
__global__ __launch_bounds__(512)
__attribute__((amdgpu_waves_per_eu(2, 2)))
void kwlstm(
        const u32* __restrict__ dtf,
        int t0, int t1, const void* __restrict__ whh,
        const float* __restrict__ Gxr,
        float* __restrict__ hallr, u32* __restrict__ hsave,
        float* __restrict__ csave) {
    if ((*dtf != 0u) != BF) return;
    const int j = threadIdx.x;
    const int u = j >> 1;              // unit 0..255
    const int k = j & 1;
    const int rowA = (k ? 256 : 0) + u;    // i or f
    const int rowB = (k ? 768 : 512) + u;  // g or o

    __shared__ __align__(16) uint4 wl[14][512];   // 114.7 KB weight tail
    __shared__ __align__(16) u32 h2[2][128];      // h as f16 pairs, dbuf

    // ---- init: weights ----
    u32 wA[100], wB[100];
    #pragma unroll
    for (int kc = 0; kc < 50; ++kc) {
        const float4 wa = ld4<BF>(whh, (size_t)rowA * 256 + kc * 4);
        wA[2 * kc]     = pk2(wa.x, wa.y);
        wA[2 * kc + 1] = pk2(wa.z, wa.w);
        const float4 wb = ld4<BF>(whh, (size_t)rowB * 256 + kc * 4);
        wB[2 * kc]     = pk2(wb.x, wb.y);
        wB[2 * kc + 1] = pk2(wb.z, wb.w);
    }
    #pragma unroll
    for (int q = 0; q < 7; ++q) {
        const float4 a0 = ld4<BF>(whh, (size_t)rowA * 256 + 200 + q * 8);
        const float4 a1 = ld4<BF>(whh, (size_t)rowA * 256 + 200 + q * 8 + 4);
        wl[q][j] = make_uint4(pk2(a0.x, a0.y), pk2(a0.z, a0.w),
                              pk2(a1.x, a1.y), pk2(a1.z, a1.w));
        const float4 b0 = ld4<BF>(whh, (size_t)rowB * 256 + 200 + q * 8);
        const float4 b1 = ld4<BF>(whh, (size_t)rowB * 256 + 200 + q * 8 + 4);
        wl[7 + q][j] = make_uint4(pk2(b0.x, b0.y), pk2(b0.z, b0.w),
                                  pk2(b1.x, b1.y), pk2(b1.z, b1.w));
    }
    // ---- init: state ----
    if (j < 128) {
        h2[0][j] = 0u; h2[1][j] = 0u;
        if (t0 > 0) h2[t0 & 1][j] = hsave[j];
    }
    float c_reg = 0.f;
    if (k == 0 && t0 > 0) c_reg = csave[u];

    // 2-deep Gx pipeline for both rows
    float gxAA = Gxr[(size_t)0 * 1024 + rowA];
    float gxAB = Gxr[(size_t)0 * 1024 + rowB];
    float gxBA = 0.f, gxBB = 0.f;
    if (t0 + 1 < t1) {
        gxBA = Gxr[(size_t)1 * 1024 + rowA];
        gxBB = Gxr[(size_t)1 * 1024 + rowB];
    }
    __syncthreads();

    for (int t = t0; t < t1; ++t) {
        const int p = t & 1;
        float gxNA = 0.f, gxNB = 0.f;              // prefetch Gx[t+2]
        if (t + 2 < t1) {
            gxNA = Gxr[(size_t)(t + 2 - t0) * 1024 + rowA];
            gxNB = Gxr[(size_t)(t + 2 - t0) * 1024 + rowB];
        }

        float aA0 = 0.f, aA1 = 0.f, aB0 = 0.f, aB1 = 0.f;
        if (t > 0) {
            const uint4* h4 = reinterpret_cast<const uint4*>(&h2[p][0]);
            #pragma unroll
            for (int q = 0; q < 25; ++q) {         // h dwords 0..99 (VGPR w)
                const uint4 hv = h4[q];            // broadcast read
                aA0 = fdot2u(wA[4 * q + 0], hv.x, aA0);
                aA1 = fdot2u(wA[4 * q + 1], hv.y, aA1);
                aA0 = fdot2u(wA[4 * q + 2], hv.z, aA0);
                aA1 = fdot2u(wA[4 * q + 3], hv.w, aA1);
                aB0 = fdot2u(wB[4 * q + 0], hv.x, aB0);
                aB1 = fdot2u(wB[4 * q + 1], hv.y, aB1);
                aB0 = fdot2u(wB[4 * q + 2], hv.z, aB0);
                aB1 = fdot2u(wB[4 * q + 3], hv.w, aB1);
            }
            #pragma unroll
            for (int q = 0; q < 7; ++q) {          // h dwords 100..127 (LDS w)
                const uint4 hv = h4[25 + q];
                const uint4 wa = wl[q][j];
                const uint4 wb = wl[7 + q][j];
                aA0 = fdot2u(wa.x, hv.x, aA0);
                aA1 = fdot2u(wa.y, hv.y, aA1);
                aA0 = fdot2u(wa.z, hv.z, aA0);
                aA1 = fdot2u(wa.w, hv.w, aA1);
                aB0 = fdot2u(wb.x, hv.x, aB0);
                aB1 = fdot2u(wb.y, hv.y, aB1);
                aB0 = fdot2u(wb.z, hv.z, aB0);
                aB1 = fdot2u(wb.w, hv.w, aB1);
            }
        }
        const float gA = (aA0 + aA1) + gxAA;       // rowA gate value
        const float gB = (aB0 + aB1) + gxAB;       // rowB gate value
        // k=0: rowA=i (sigm), rowB=g (tanh); k=1: rowA=f (sigm), rowB=o (sigm)
        const float actA = sigm(gA);
        const float actB = k ? sigm(gB) : tanh_fast(gB);
        const float xfA = __shfl_xor(actA, 1, 64); // k=0 <- sigm(f)
        const float xfB = __shfl_xor(actB, 1, 64); // k=0 <- sigm(o)
        float hn = 0.f;
        if (k == 0) {
            const float cn = xfA * c_reg + actA * actB;
            c_reg = cn;
            hn = xfB * tanh_fast(cn);
            hallr[(size_t)(t - t0) * 256 + u] = hn;
        }
        const float ho = __shfl_xor(hn, 2, 64);    // j=4m <- hn(u+1)
        if ((j & 3) == 0) h2[p ^ 1][u >> 1] = pk2(hn, ho);
        __syncthreads();                           // h2[p^1] ready for t+1
        gxAA = gxBA; gxAB = gxBB; gxBA = gxNA; gxBB = gxNB;
    }
    // ---- save state for next chunk ----
    if (j < 128) hsave[j] = h2[t1 & 1][j];
    if (k == 0)  csave[u] = c_reg;
}

// ---------------------------------------------------------------------------
// Kernel D: logits + log_softmax. One wave per word.
// ---------------------------------------------------------------------------
template <bool BF>
__global__ __launch_bounds__(64) void ktag(
        const u32* __restrict__ dtf,
        int t0, const float* __restrict__ hallr, const void* __restrict__ tagW,
        const void* __restrict__ tagb, void* __restrict__ out) {
    if ((*dtf != 0u) != BF) return;
    const int tr = blockIdx.x, j = threadIdx.x;
    const int t = t0 + tr;
    __shared__ __align__(16) float4 h4[64];
    h4[j] = reinterpret_cast<const float4*>(hallr + (size_t)tr * 256)[j];
    __syncthreads();
    float logit = -1e30f;
    if (j < NTAGS) {
        float a0 = 0.f, a1 = 0.f, a2 = 0.f, a3 = 0.f;
        #pragma unroll
        for (int kc = 0; kc < 64; ++kc) {
            const float4 wvv = ld4<BF>(tagW, (size_t)j * 256 + kc * 4);
            const float4 hv = h4[kc];
            a0 = fmaf(wvv.x, hv.x, a0); a1 = fmaf(wvv.y, hv.y, a1);
            a2 = fmaf(wvv.z, hv.z, a2); a3 = fmaf(wvv.w, hv.w, a3);
        }
        logit = ld1<BF>(tagb, j) + ((a0 + a1) + (a2 + a3));
    }
    float m = logit;
    #pragma unroll
    for (int off = 32; off >= 1; off >>= 1) m = fmaxf(m, __shfl_xor(m, off, 64));
    const float e = (j < NTAGS) ? __expf(logit - m) : 0.f;
    float ssum = e;
    #pragma unroll
    for (int off = 32; off >= 1; off >>= 1) ssum += __shfl_xor(ssum, off, 64);
    if (j < NTAGS)
        st1<BF>(out, (size_t)t * NTAGS + j, logit - m - __logf(ssum));
}

// ---------------------------------------------------------------------------
extern "C" void kernel_launch(void* const* d_in, const int* in_sizes, int n_in,
                              void* d_out, int out_size, void* d_ws, size_t ws_size,
                              hipStream_t stream) {
    const int*  word_idxs = (const int*)d_in[0];
    const int*  char_idxs = (const int*)d_in[1];
    const int*  char_lens = (const int*)d_in[2];
    const void* char_emb  = d_in[3];
    const void* char_Wih  = d_in[4];
    const void* char_Whh  = d_in[5];
    const void* char_bih  = d_in[6];
    const void* char_bhh  = d_in[7];
    const void* word_emb  = d_in[8];
    const void* word_Wih  = d_in[9];
    const void* word_Whh  = d_in[10];
    const void* word_bih  = d_in[11];
    const void* word_bhh  = d_in[12];
    const void* tag_W     = d_in[13];
    const void* tag_b     = d_in[14];

    // ws layout:
    //   [0,64)        dtflag u32
    //   [64,576)      hsave u32[128] (f16-pair h carry across chunks)
    //   [4224,5248)   csave f32[256]
    //   [8192,+2MB)   cfeat f32[8192*64]
    //   [ring0,...)   Gx ring f32[CT*1024] + hall ring f32[CT*256]
    char* ws = (char*)d_ws;
    u32*   dtf    = (u32*)(ws);
    u32*   hsave  = (u32*)(ws + 64);
    float* csave  = (float*)(ws + 4224);
    float* cfeat  = (float*)(ws + 8192);
    const size_t ring0 = 8192 + (size_t)S_LEN * CH * 4;

    int NC = 256;
    const int ncs[9] = {1, 2, 4, 8, 16, 32, 64, 128, 256};
    for (int i = 0; i < 9; ++i) {
        const int ct = S_LEN / ncs[i];
        if (ring0 + (size_t)ct * 5120 <= ws_size) { NC = ncs[i]; break; }
    }
    const int CT = S_LEN / NC;
    float* Gxr   = (float*)(ws + ring0);
    float* hallr = (float*)(ws + ring0 + (size_t)CT * 4096);

    hipLaunchKernelGGL(kdetect, dim3(1), dim3(64), 0, stream, char_emb, dtf);
    hipLaunchKernelGGL(kchar<true>,  dim3(S_LEN / 8), dim3(256), 0, stream,
                       dtf, char_idxs, char_lens, char_emb, char_Wih, char_Whh,
                       char_bih, char_bhh, cfeat);
    hipLaunchKernelGGL(kchar<false>, dim3(S_LEN / 8), dim3(256), 0, stream,
                       dtf, char_idxs, char_lens, char_emb, char_Wih, char_Whh,
                       char_bih, char_bhh, cfeat);
    for (int c = 0; c < NC; ++c) {
        const int t0 = c * CT;
        hipLaunchKernelGGL(kgx<true>,  dim3(CT / 16), dim3(256), 0, stream,
                           dtf, t0, word_idxs, cfeat, word_emb, word_Wih,
                           word_bih, word_bhh, Gxr);
        hipLaunchKernelGGL(kgx<false>, dim3(CT / 16), dim3(256), 0, stream,
                           dtf, t0, word_idxs, cfeat, word_emb, word_Wih,
                           word_bih, word_bhh, Gxr);
        hipLaunchKernelGGL(kwlstm<true>,  dim3(1), dim3(512), 0, stream,
                           dtf, t0, t0 + CT, word_Whh, Gxr, hallr, hsave, csave);
        hipLaunchKernelGGL(kwlstm<false>, dim3(1), dim3(512), 0, stream,
                           dtf, t0, t0 + CT, word_Whh, Gxr, hallr, hsave, csave);
        hipLaunchKernelGGL(ktag<true>,  dim3(CT), dim3(64), 0, stream,
                           dtf, t0, hallr, tag_W, tag_b, d_out);
        hipLaunchKernelGGL(ktag<false>, dim3(CT), dim3(64), 0, stream,
                           dtf, t0, hallr, tag_W, tag_b, d_out);
    }
}